// Round 6
// baseline (336.548 us; speedup 1.0000x reference)
//
#include <hip/hip_runtime.h>
#include <stdint.h>

typedef __attribute__((ext_vector_type(8))) __bf16 bf16x8;
typedef __attribute__((ext_vector_type(4))) float f32x4;
typedef __attribute__((ext_vector_type(16))) float f32x16;
typedef __attribute__((ext_vector_type(4))) uint32_t u32x4;

#define DEVINL __device__ __forceinline__

constexpr int Bc = 2, Sc = 2048, Dc = 1024, Hc = 16;
constexpr int MSc = Bc * Sc;  // 4096 total rows
constexpr float LN_EPS_C = 1e-3f;
constexpr float QSCALE = 0.125f * 1.44269504f;  // 1/sqrt(64) * log2(e)

// ---- global -> LDS direct load, 16B per lane (wave-uniform LDS base).
DEVINL void gload16(const void* gsrc, const void* lds_dst) {
  auto g = (const __attribute__((address_space(1))) void*)(uintptr_t)gsrc;
  auto l = (__attribute__((address_space(3))) void*)(uint32_t)(uintptr_t)lds_dst;
  __builtin_amdgcn_global_load_lds(g, l, 16, 0, 0);
}

// packed f32 pair -> 2x bf16 in one u32 (T12 recipe; no builtin on gfx950)
DEVINL uint32_t cvtpk(float lo, float hi) {
  uint32_t r;
  asm("v_cvt_pk_bf16_f32 %0, %1, %2" : "=v"(r) : "v"(lo), "v"(hi));
  return r;
}

// v_permlane32_swap: a[32:63] <-> b[0:31]
DEVINL void plswap(uint32_t& a, uint32_t& b) {
  asm volatile("v_permlane32_swap_b32 %0, %1" : "+v"(a), "+v"(b));
}

// =====================================================================
// GEMM: C[M,N] = A[M,K] * Bt[N,K]^T   (A, Bt bf16 row-major, K-contiguous)
// 128xBN tile, BK=64, 256 threads = 4 waves in 2x2, 16x16x32 bf16 MFMA.
// LDS XOR-swizzled via pre-swizzled global source (global_load_lds linear).
// EPI: 0 = bf16, 1 = f32, 2 = relu->bf16, 3 = bf16 with QSCALE on col<1024
// =====================================================================
template <int EPI, int BN>
__global__ __launch_bounds__(256) void gemm_bt(const __bf16* __restrict__ A,
                                               const __bf16* __restrict__ Bt,
                                               void* __restrict__ Cout,
                                               int M, int N, int K) {
  __shared__ __bf16 Ash[128 * 64];
  __shared__ __bf16 Bsh[BN * 64];
  constexpr int NF = BN / 32;  // per-wave n-fragments
  const int t = threadIdx.x;
  const int lane = t & 63;
  const int wid = t >> 6;
  const int nbn = N / BN;
  const int bm = blockIdx.x / nbn, bn = blockIdx.x % nbn;
  const int m0 = bm * 128, n0 = bn * BN;
  const int wm = wid >> 1, wn = wid & 1;

  f32x4 acc[4][NF];
  f32x4 zero = {0.f, 0.f, 0.f, 0.f};
#pragma unroll
  for (int i = 0; i < 4; ++i)
#pragma unroll
    for (int j = 0; j < NF; ++j) acc[i][j] = zero;

  for (int k0 = 0; k0 < K; k0 += 64) {
#pragma unroll
    for (int i = 0; i < 4; ++i) {
      int c = i * 256 + t;
      int row = c >> 3;
      int ch = (c & 7) ^ (row & 7);
      gload16(A + (size_t)(m0 + row) * K + k0 + ch * 8,
              (const char*)Ash + (i * 256 + wid * 64) * 16);
    }
#pragma unroll
    for (int i = 0; i < BN / 32; ++i) {
      int c = i * 256 + t;
      int row = c >> 3;
      int ch = (c & 7) ^ (row & 7);
      gload16(Bt + (size_t)(n0 + row) * K + k0 + ch * 8,
              (const char*)Bsh + (i * 256 + wid * 64) * 16);
    }
    __syncthreads();
#pragma unroll
    for (int kk = 0; kk < 2; ++kk) {
      bf16x8 af[4], bfr[NF];
      const int colb = kk * 64 + (lane >> 4) * 16;
#pragma unroll
      for (int mf = 0; mf < 4; ++mf) {
        int row = wm * 64 + mf * 16 + (lane & 15);
        af[mf] = *(const bf16x8*)((const char*)Ash + row * 128 +
                                  (colb ^ ((row & 7) << 4)));
      }
#pragma unroll
      for (int nf = 0; nf < NF; ++nf) {
        int row = wn * (BN / 2) + nf * 16 + (lane & 15);
        bfr[nf] = *(const bf16x8*)((const char*)Bsh + row * 128 +
                                   (colb ^ ((row & 7) << 4)));
      }
#pragma unroll
      for (int mf = 0; mf < 4; ++mf)
#pragma unroll
        for (int nf = 0; nf < NF; ++nf)
          acc[mf][nf] = __builtin_amdgcn_mfma_f32_16x16x32_bf16(
              af[mf], bfr[nf], acc[mf][nf], 0, 0, 0);
    }
    __syncthreads();
  }
#pragma unroll
  for (int mf = 0; mf < 4; ++mf)
#pragma unroll
    for (int nf = 0; nf < NF; ++nf)
#pragma unroll
      for (int r = 0; r < 4; ++r) {
        int row = m0 + wm * 64 + mf * 16 + (lane >> 4) * 4 + r;
        int col = n0 + wn * (BN / 2) + nf * 16 + (lane & 15);
        float v = acc[mf][nf][r];
        if (EPI == 0)
          ((__bf16*)Cout)[(size_t)row * N + col] = (__bf16)v;
        else if (EPI == 1)
          ((float*)Cout)[(size_t)row * N + col] = v;
        else if (EPI == 2)
          ((__bf16*)Cout)[(size_t)row * N + col] = (__bf16)fmaxf(v, 0.f);
        else {
          if (col < 1024) v *= QSCALE;
          ((__bf16*)Cout)[(size_t)row * N + col] = (__bf16)v;
        }
      }
}

// =====================================================================
// Flash attention, swapped-QK 32x32, no-max softmax, NO LDS (K/V L1/L2-fit:
// 512KB per (b,h); staging through LDS was pure overhead — barriers + LDS
// pipe were ~50% of time). K/V fragments loaded global->VGPR: each K-row
// touch is one aligned 128B line (d-range h*64..h*64+64), perfect line use.
// No barriers -> waves are independent streams; V(t) loads covered by
// QK+softmax, K(t+1) ping-pong prefetch covered by softmax+PV (counted
// vmcnt by compiler; no barrier to defeat it). XCD-clustered block swizzle:
// all 16 q-blocks of a (b,h) on one XCD -> K/V from HBM once, L2-reused.
// =====================================================================
__global__ __launch_bounds__(256) void attn_kernel(const __bf16* __restrict__ QK,
                                                   const __bf16* __restrict__ Vt,
                                                   __bf16* __restrict__ ctx) {
  const int t = threadIdx.x, lane = t & 63, wid = t >> 6;
  // bijective swizzle: flat -> (bh, qt); bh determined by flat%8 (XCD id)
  const int flat = blockIdx.x;  // 0..511
  const int bh = (flat & 7) * 4 + ((flat >> 3) & 3);  // 0..31
  const int qt = flat >> 5;                           // 0..15
  const int b = bh >> 4, h = bh & 15;
  const int q0w = qt * 128 + wid * 32;
  const int ql = lane & 31, hl = lane >> 5;

  // Q as B-operand frags: col=q=lane&31, k=d = kk*16 + hl*8 + j (pre-scaled)
  bf16x8 qf[4];
#pragma unroll
  for (int kk = 0; kk < 4; ++kk)
    qf[kk] = *(const bf16x8*)(QK + (size_t)(b * Sc + q0w + ql) * 2048 + h * 64 +
                              kk * 16 + hl * 8);

  // per-lane base pointers (advance via compile-time offsets only)
  const __bf16* Kb = QK + 1024 + (size_t)(b * Sc + ql) * 2048 + h * 64 + hl * 8;
  const __bf16* Vb = Vt + (size_t)(h * 64 + ql) * MSc + b * Sc + hl * 8;

  f32x16 oacc[2];
#pragma unroll
  for (int r = 0; r < 16; ++r) {
    oacc[0][r] = 0.f;
    oacc[1][r] = 0.f;
  }
  float l0 = 0.f, l1 = 0.f;

  bf16x8 kA[4][2], kB[4][2];
  auto loadK = [&](bf16x8(&kf)[4][2], int kt) {
#pragma unroll
    for (int kk = 0; kk < 4; ++kk)
#pragma unroll
      for (int mf = 0; mf < 2; ++mf)
        kf[kk][mf] = *(const bf16x8*)(Kb + (size_t)(kt * 64 + mf * 32) * 2048 +
                                      kk * 16);
  };
  loadK(kA, 0);

  auto body = [&](bf16x8(&cur)[4][2], bf16x8(&nxt)[4][2], int kt) {
    // ---- V loads for this tile (consumed ~500cyc later at PV)
    bf16x8 vf[4][2];
#pragma unroll
    for (int kt2 = 0; kt2 < 4; ++kt2)
#pragma unroll
      for (int nh = 0; nh < 2; ++nh)
        vf[kt2][nh] = *(const bf16x8*)(Vb + (size_t)nh * 32 * MSc + kt * 64 +
                                       kt2 * 16);

    // ---- S^T[ks][q] = K Q^T
    f32x16 sacc[2];
#pragma unroll
    for (int mf = 0; mf < 2; ++mf)
#pragma unroll
      for (int r = 0; r < 16; ++r) sacc[mf][r] = 0.f;
    __builtin_amdgcn_s_setprio(1);
#pragma unroll
    for (int kk = 0; kk < 4; ++kk)
#pragma unroll
      for (int mf = 0; mf < 2; ++mf)
        sacc[mf] = __builtin_amdgcn_mfma_f32_32x32x16_bf16(cur[kk][mf], qf[kk],
                                                           sacc[mf], 0, 0, 0);
    __builtin_amdgcn_s_setprio(0);

    // ---- K prefetch for next tile (clamped; covered by softmax+PV)
    const int ktn = kt + 1 < Sc / 64 ? kt + 1 : Sc / 64 - 1;
    loadK(nxt, ktn);

    // ---- p = exp2(s); accumulate l (2 chains); pack to PV B-frags
    bf16x8 pb[4];
#pragma unroll
    for (int mf = 0; mf < 2; ++mf) {
      float p[16];
#pragma unroll
      for (int r = 0; r < 16; ++r) {
        p[r] = __builtin_exp2f(sacc[mf][r]);
        if (r & 1)
          l1 += p[r];
        else
          l0 += p[r];
      }
#pragma unroll
      for (int g = 0; g < 2; ++g) {
        uint32_t wa = cvtpk(p[8 * g + 0], p[8 * g + 1]);
        uint32_t wb = cvtpk(p[8 * g + 4], p[8 * g + 5]);
        uint32_t wc = cvtpk(p[8 * g + 2], p[8 * g + 3]);
        uint32_t wd = cvtpk(p[8 * g + 6], p[8 * g + 7]);
        plswap(wa, wb);
        plswap(wc, wd);
        u32x4 uw;
        uw.x = wa;  // j=0,1
        uw.y = wc;  // j=2,3
        uw.z = wb;  // j=4,5
        uw.w = wd;  // j=6,7
        pb[mf * 2 + g] = __builtin_bit_cast(bf16x8, uw);
      }
    }

    // ---- O^T += V^T P^T
    __builtin_amdgcn_s_setprio(1);
#pragma unroll
    for (int kt2 = 0; kt2 < 4; ++kt2)
#pragma unroll
      for (int nh = 0; nh < 2; ++nh)
        oacc[nh] = __builtin_amdgcn_mfma_f32_32x32x16_bf16(vf[kt2][nh], pb[kt2],
                                                           oacc[nh], 0, 0, 0);
    __builtin_amdgcn_s_setprio(0);
  };

  for (int kp = 0; kp < Sc / 128; ++kp) {  // ping-pong K register sets
    body(kA, kB, 2 * kp);
    body(kB, kA, 2 * kp + 1);
  }

  // ---- l: per-lane covers 32 ks-slots; lane^32 has the complement
  const float l_run = l0 + l1;
  const float l_tot = l_run + __shfl_xor(l_run, 32);
  const float inv_l = 1.f / l_tot;
#pragma unroll
  for (int nh = 0; nh < 2; ++nh)
#pragma unroll
    for (int g = 0; g < 4; ++g) {
      union {
        __bf16 hv[4];
        uint2 u;
      } w;
#pragma unroll
      for (int r = 0; r < 4; ++r)
        w.hv[r] = (__bf16)(oacc[nh][4 * g + r] * inv_l);
      int dh0 = nh * 32 + 8 * g + 4 * hl;
      *(uint2*)(ctx + (size_t)(b * Sc + q0w + ql) * Dc + h * 64 + dh0) = w.u;
    }
}

// =====================================================================
// LayerNorm over last dim (1024) of X+R, one row per block (256 thr).
// MODE 0: write bf16 + f32 residual; MODE 1: f32 only.
// =====================================================================
template <int MODE>
__global__ __launch_bounds__(256) void ln_fused(const float* __restrict__ X,
                                                const float* __restrict__ R,
                                                const float* __restrict__ gamma,
                                                const float* __restrict__ beta,
                                                __bf16* __restrict__ out_bf,
                                                float* __restrict__ out_f) {
  const int row = blockIdx.x;
  const int t = threadIdx.x;
  const f32x4 xv = *(const f32x4*)(X + (size_t)row * Dc + t * 4);
  const f32x4 rv = *(const f32x4*)(R + (size_t)row * Dc + t * 4);
  float x[4];
  float s = 0.f, ss = 0.f;
#pragma unroll
  for (int i = 0; i < 4; ++i) {
    x[i] = xv[i] + rv[i];
    s += x[i];
    ss += x[i] * x[i];
  }
#pragma unroll
  for (int m = 1; m < 64; m <<= 1) {
    s += __shfl_xor(s, m);
    ss += __shfl_xor(ss, m);
  }
  __shared__ float sred[8];
  const int wid = t >> 6, lane = t & 63;
  if (lane == 0) {
    sred[wid * 2] = s;
    sred[wid * 2 + 1] = ss;
  }
  __syncthreads();
  s = sred[0] + sred[2] + sred[4] + sred[6];
  ss = sred[1] + sred[3] + sred[5] + sred[7];
  const float mu = s * (1.f / Dc);
  const float var = ss * (1.f / Dc) - mu * mu;
  const float rstd = rsqrtf(var + LN_EPS_C);
  const f32x4 gv = *(const f32x4*)(gamma + t * 4);
  const f32x4 bv = *(const f32x4*)(beta + t * 4);
#pragma unroll
  for (int i = 0; i < 4; ++i) {
    float y = (x[i] - mu) * rstd * gv[i] + bv[i];
    if (MODE == 0) {
      out_bf[(size_t)row * Dc + t * 4 + i] = (__bf16)y;
      out_f[(size_t)row * Dc + t * 4 + i] = y;
    } else {
      out_f[(size_t)row * Dc + t * 4 + i] = y;
    }
  }
}

// ---- transpose + cast all six weights: W[fi][fo] f32 -> Wt[fo][fi] bf16
__global__ __launch_bounds__(256) void wtrans(const float* __restrict__ w0,
                                              const float* __restrict__ w1,
                                              const float* __restrict__ w2,
                                              const float* __restrict__ w3,
                                              const float* __restrict__ w4,
                                              const float* __restrict__ w5,
                                              __bf16* __restrict__ out) {
  const float* ws[6] = {w0, w1, w2, w3, w4, w5};
  const float* w = ws[blockIdx.z];
  __bf16* o = out + (size_t)blockIdx.z * Dc * Dc;
  __shared__ float tile[32][33];
  const int tx = threadIdx.x, ty = threadIdx.y;  // 32 x 8
  const int c0 = blockIdx.x * 32, r0 = blockIdx.y * 32;
#pragma unroll
  for (int i = 0; i < 4; ++i)
    tile[ty + i * 8][tx] = w[(size_t)(r0 + ty + i * 8) * Dc + c0 + tx];
  __syncthreads();
#pragma unroll
  for (int i = 0; i < 4; ++i)
    o[(size_t)(c0 + ty + i * 8) * Dc + r0 + tx] = (__bf16)tile[tx][ty + i * 8];
}

// ---- f32 -> bf16 cast, 4 elements/thread
__global__ __launch_bounds__(256) void castq(const float* __restrict__ in,
                                             __bf16* __restrict__ out, int n4) {
  int i = blockIdx.x * blockDim.x + threadIdx.x;
  if (i < n4) {
    f32x4 v = *(const f32x4*)(in + (size_t)i * 4);
#pragma unroll
    for (int j = 0; j < 4; ++j) out[(size_t)i * 4 + j] = (__bf16)v[j];
  }
}

extern "C" void kernel_launch(void* const* d_in, const int* in_sizes, int n_in,
                              void* d_out, int out_size, void* d_ws,
                              size_t ws_size, hipStream_t stream) {
  const float* query = (const float*)d_in[0];
  const float* Wq = (const float*)d_in[1];
  const float* Wk = (const float*)d_in[2];
  const float* Wv = (const float*)d_in[3];
  const float* W1 = (const float*)d_in[4];
  const float* W2 = (const float*)d_in[5];
  const float* W3 = (const float*)d_in[6];
  const float* gamma = (const float*)d_in[7];
  const float* beta = (const float*)d_in[8];
  float* out = (float*)d_out;

  char* ws = (char*)d_ws;
  const size_t MB = 1u << 20;
  __bf16* Wt = (__bf16*)(ws);              // 6 x 2MB: [Wq;Wk;Wv;W1;W2;W3]^T
  __bf16* Xbf = (__bf16*)(ws + 12 * MB);   // 8MB
  __bf16* QKb = (__bf16*)(ws + 20 * MB);   // 16MB  [4096 x 2048] = [Q*c | K]
  __bf16* Vt = (__bf16*)(ws + 36 * MB);    // 8MB   V^T [D, B*S]
  __bf16* Ctx = (__bf16*)(ws + 44 * MB);   // 8MB
  float* T1 = (float*)(ws + 52 * MB);      // 16MB (reused for T3)
  __bf16* Rbf = (__bf16*)(ws + 68 * MB);   // 8MB
  float* Rf = (float*)(ws + 76 * MB);      // 16MB
  __bf16* H2 = (__bf16*)(ws + 92 * MB);    // 8MB

  const int WD = Dc * Dc;

  wtrans<<<dim3(32, 32, 6), dim3(32, 8), 0, stream>>>(Wq, Wk, Wv, W1, W2, W3, Wt);
  castq<<<4096, 256, 0, stream>>>(query, Xbf, (MSc * Dc) / 4);
  // [Q*c | K] = X [Wq | Wk]  (fused, N=2048, 512 blocks, Q pre-scaled)
  gemm_bt<3, 128><<<32 * 16, 256, 0, stream>>>(Xbf, Wt, QKb, MSc, 2048, Dc);
  // V^T = Wv^T X^T : (A=Wv_t [D,D], Bt=X [B*S,D]) -> [D, B*S]; BN=64 -> 512 blk
  gemm_bt<0, 64><<<8 * 64, 256, 0, stream>>>(Wt + 2 * WD, Xbf, Vt, Dc, MSc, Dc);
  attn_kernel<<<512, 256, 0, stream>>>(QKb, Vt, Ctx);
  // T1 = ctx W1 (f32)
  gemm_bt<1, 64><<<32 * 16, 256, 0, stream>>>(Ctx, Wt + 3 * WD, T1, MSc, Dc, Dc);
  // residual = LN(T1 + query) -> Rbf (bf16) + Rf (f32)
  ln_fused<0><<<MSc, 256, 0, stream>>>(T1, query, gamma, beta, Rbf, Rf);
  // H2 = relu(residual W2) (bf16)
  gemm_bt<2, 64><<<32 * 16, 256, 0, stream>>>(Rbf, Wt + 4 * WD, H2, MSc, Dc, Dc);
  // T1 = H2 W3 (f32)
  gemm_bt<1, 64><<<32 * 16, 256, 0, stream>>>(H2, Wt + 5 * WD, T1, MSc, Dc, Dc);
  // out = LN(T1 + residual)
  ln_fused<1><<<MSc, 256, 0, stream>>>(T1, Rf, gamma, beta, nullptr, out);
}

// Round 7
// 300.501 us; speedup vs baseline: 1.1200x; 1.1200x over previous
//
#include <hip/hip_runtime.h>
#include <stdint.h>

typedef __attribute__((ext_vector_type(8))) __bf16 bf16x8;
typedef __attribute__((ext_vector_type(4))) float f32x4;
typedef __attribute__((ext_vector_type(16))) float f32x16;
typedef __attribute__((ext_vector_type(4))) uint32_t u32x4;

#define DEVINL __device__ __forceinline__

constexpr int Bc = 2, Sc = 2048, Dc = 1024, Hc = 16;
constexpr int MSc = Bc * Sc;  // 4096 total rows
constexpr float LN_EPS_C = 1e-3f;
constexpr float QSCALE = 0.125f * 1.44269504f;  // 1/sqrt(64) * log2(e)

// ---- global -> LDS direct load, 16B per lane (wave-uniform LDS base).
DEVINL void gload16(const void* gsrc, const void* lds_dst) {
  auto g = (const __attribute__((address_space(1))) void*)(uintptr_t)gsrc;
  auto l = (__attribute__((address_space(3))) void*)(uint32_t)(uintptr_t)lds_dst;
  __builtin_amdgcn_global_load_lds(g, l, 16, 0, 0);
}

// packed f32 pair -> 2x bf16 in one u32
DEVINL uint32_t cvtpk(float lo, float hi) {
  uint32_t r;
  asm("v_cvt_pk_bf16_f32 %0, %1, %2" : "=v"(r) : "v"(lo), "v"(hi));
  return r;
}

// v_permlane32_swap: a[32:63] <-> b[0:31]
DEVINL void plswap(uint32_t& a, uint32_t& b) {
  asm volatile("v_permlane32_swap_b32 %0, %1" : "+v"(a), "+v"(b));
}

// =====================================================================
// GEMM: C[M,N] = A[M,K] * Bt[N,K]^T   (A, Bt bf16 row-major, K-contiguous)
// 128xBN tile, BK=64, 256 threads = 4 waves in 2x2, 16x16x32 bf16 MFMA.
// LDS XOR-swizzled via pre-swizzled global source (global_load_lds linear).
// EPI: 0 = bf16, 1 = f32, 2 = relu->bf16, 3 = bf16 with QSCALE on col<1024
// =====================================================================
template <int EPI, int BN>
__global__ __launch_bounds__(256) void gemm_bt(const __bf16* __restrict__ A,
                                               const __bf16* __restrict__ Bt,
                                               void* __restrict__ Cout,
                                               int M, int N, int K) {
  __shared__ __bf16 Ash[128 * 64];
  __shared__ __bf16 Bsh[BN * 64];
  constexpr int NF = BN / 32;
  const int t = threadIdx.x;
  const int lane = t & 63;
  const int wid = t >> 6;
  const int nbn = N / BN;
  const int bm = blockIdx.x / nbn, bn = blockIdx.x % nbn;
  const int m0 = bm * 128, n0 = bn * BN;
  const int wm = wid >> 1, wn = wid & 1;

  f32x4 acc[4][NF];
  f32x4 zero = {0.f, 0.f, 0.f, 0.f};
#pragma unroll
  for (int i = 0; i < 4; ++i)
#pragma unroll
    for (int j = 0; j < NF; ++j) acc[i][j] = zero;

  for (int k0 = 0; k0 < K; k0 += 64) {
#pragma unroll
    for (int i = 0; i < 4; ++i) {
      int c = i * 256 + t;
      int row = c >> 3;
      int ch = (c & 7) ^ (row & 7);
      gload16(A + (size_t)(m0 + row) * K + k0 + ch * 8,
              (const char*)Ash + (i * 256 + wid * 64) * 16);
    }
#pragma unroll
    for (int i = 0; i < BN / 32; ++i) {
      int c = i * 256 + t;
      int row = c >> 3;
      int ch = (c & 7) ^ (row & 7);
      gload16(Bt + (size_t)(n0 + row) * K + k0 + ch * 8,
              (const char*)Bsh + (i * 256 + wid * 64) * 16);
    }
    __syncthreads();
#pragma unroll
    for (int kk = 0; kk < 2; ++kk) {
      bf16x8 af[4], bfr[NF];
      const int colb = kk * 64 + (lane >> 4) * 16;
#pragma unroll
      for (int mf = 0; mf < 4; ++mf) {
        int row = wm * 64 + mf * 16 + (lane & 15);
        af[mf] = *(const bf16x8*)((const char*)Ash + row * 128 +
                                  (colb ^ ((row & 7) << 4)));
      }
#pragma unroll
      for (int nf = 0; nf < NF; ++nf) {
        int row = wn * (BN / 2) + nf * 16 + (lane & 15);
        bfr[nf] = *(const bf16x8*)((const char*)Bsh + row * 128 +
                                   (colb ^ ((row & 7) << 4)));
      }
#pragma unroll
      for (int mf = 0; mf < 4; ++mf)
#pragma unroll
        for (int nf = 0; nf < NF; ++nf)
          acc[mf][nf] = __builtin_amdgcn_mfma_f32_16x16x32_bf16(
              af[mf], bfr[nf], acc[mf][nf], 0, 0, 0);
    }
    __syncthreads();
  }
#pragma unroll
  for (int mf = 0; mf < 4; ++mf)
#pragma unroll
    for (int nf = 0; nf < NF; ++nf)
#pragma unroll
      for (int r = 0; r < 4; ++r) {
        int row = m0 + wm * 64 + mf * 16 + (lane >> 4) * 4 + r;
        int col = n0 + wn * (BN / 2) + nf * 16 + (lane & 15);
        float v = acc[mf][nf][r];
        if (EPI == 0)
          ((__bf16*)Cout)[(size_t)row * N + col] = (__bf16)v;
        else if (EPI == 1)
          ((float*)Cout)[(size_t)row * N + col] = v;
        else if (EPI == 2)
          ((__bf16*)Cout)[(size_t)row * N + col] = (__bf16)fmaxf(v, 0.f);
        else {
          if (col < 1024) v *= QSCALE;
          ((__bf16*)Cout)[(size_t)row * N + col] = (__bf16)v;
        }
      }
}

// ---- split-K=2 variant: slice s computes K-range [s*K/2,(s+1)*K/2) into
// f32 partial Cs; combine happens in the consuming LayerNorm (free).
// Grid = 2 * (M/128)*(N/BN) -> 4 blocks/CU for N=1024, BN=64.
template <int BN>
__global__ __launch_bounds__(256) void gemm_bt_sk2(const __bf16* __restrict__ A,
                                                   const __bf16* __restrict__ Bt,
                                                   float* __restrict__ C0,
                                                   float* __restrict__ C1,
                                                   int M, int N, int K) {
  __shared__ __bf16 Ash[128 * 64];
  __shared__ __bf16 Bsh[BN * 64];
  constexpr int NF = BN / 32;
  const int t = threadIdx.x;
  const int lane = t & 63;
  const int wid = t >> 6;
  const int nbn = N / BN;
  const int nb = (M / 128) * nbn;
  int blk = blockIdx.x;
  int ks = 0;
  float* Cout = C0;
  if (blk >= nb) {
    blk -= nb;
    ks = K / 2;
    Cout = C1;
  }
  const int bm = blk / nbn, bn = blk % nbn;
  const int m0 = bm * 128, n0 = bn * BN;
  const int wm = wid >> 1, wn = wid & 1;

  f32x4 acc[4][NF];
  f32x4 zero = {0.f, 0.f, 0.f, 0.f};
#pragma unroll
  for (int i = 0; i < 4; ++i)
#pragma unroll
    for (int j = 0; j < NF; ++j) acc[i][j] = zero;

  for (int k0 = ks; k0 < ks + K / 2; k0 += 64) {
#pragma unroll
    for (int i = 0; i < 4; ++i) {
      int c = i * 256 + t;
      int row = c >> 3;
      int ch = (c & 7) ^ (row & 7);
      gload16(A + (size_t)(m0 + row) * K + k0 + ch * 8,
              (const char*)Ash + (i * 256 + wid * 64) * 16);
    }
#pragma unroll
    for (int i = 0; i < BN / 32; ++i) {
      int c = i * 256 + t;
      int row = c >> 3;
      int ch = (c & 7) ^ (row & 7);
      gload16(Bt + (size_t)(n0 + row) * K + k0 + ch * 8,
              (const char*)Bsh + (i * 256 + wid * 64) * 16);
    }
    __syncthreads();
#pragma unroll
    for (int kk = 0; kk < 2; ++kk) {
      bf16x8 af[4], bfr[NF];
      const int colb = kk * 64 + (lane >> 4) * 16;
#pragma unroll
      for (int mf = 0; mf < 4; ++mf) {
        int row = wm * 64 + mf * 16 + (lane & 15);
        af[mf] = *(const bf16x8*)((const char*)Ash + row * 128 +
                                  (colb ^ ((row & 7) << 4)));
      }
#pragma unroll
      for (int nf = 0; nf < NF; ++nf) {
        int row = wn * (BN / 2) + nf * 16 + (lane & 15);
        bfr[nf] = *(const bf16x8*)((const char*)Bsh + row * 128 +
                                   (colb ^ ((row & 7) << 4)));
      }
#pragma unroll
      for (int mf = 0; mf < 4; ++mf)
#pragma unroll
        for (int nf = 0; nf < NF; ++nf)
          acc[mf][nf] = __builtin_amdgcn_mfma_f32_16x16x32_bf16(
              af[mf], bfr[nf], acc[mf][nf], 0, 0, 0);
    }
    __syncthreads();
  }
#pragma unroll
  for (int mf = 0; mf < 4; ++mf)
#pragma unroll
    for (int nf = 0; nf < NF; ++nf)
#pragma unroll
      for (int r = 0; r < 4; ++r) {
        int row = m0 + wm * 64 + mf * 16 + (lane >> 4) * 4 + r;
        int col = n0 + wn * (BN / 2) + nf * 16 + (lane & 15);
        Cout[(size_t)row * N + col] = acc[mf][nf][r];
      }
}

// =====================================================================
// Flash attention, swapped-QK 32x32, no-max softmax (r4 structure) +
// 4-buffer LDS / 2 tiles per barrier period (stages issued at period
// start -> full period of latency cover; half the barrier/drain count)
// + XCD-clustered block swizzle (r6-proven: FETCH 102->12MB).
// =====================================================================
__global__ __launch_bounds__(256) void attn_kernel(const __bf16* __restrict__ QK,
                                                   const __bf16* __restrict__ Vt,
                                                   __bf16* __restrict__ ctx) {
  __shared__ __bf16 Ksh[4][64 * 64];
  __shared__ __bf16 Vsh[4][64 * 64];
  const int t = threadIdx.x, lane = t & 63, wid = t >> 6;
  // bijective swizzle: all 16 q-blocks of a (b,h) on one XCD
  const int flat = blockIdx.x;                        // 0..511
  const int bh = (flat & 7) * 4 + ((flat >> 3) & 3);  // 0..31
  const int qt = flat >> 5;                           // 0..15
  const int b = bh >> 4, h = bh & 15;
  const int q0w = qt * 128 + wid * 32;
  const int ql = lane & 31, hl = lane >> 5;

  const __bf16* Qp = QK;         // ld 2048, pre-scaled by QSCALE
  const __bf16* Kp = QK + 1024;  // ld 2048

  // Q as B-operand frags: col=q=lane&31, k=d = kk*16 + hl*8 + j
  bf16x8 qf[4];
#pragma unroll
  for (int kk = 0; kk < 4; ++kk)
    qf[kk] = *(const bf16x8*)(Qp + (size_t)(b * Sc + q0w + ql) * 2048 + h * 64 +
                              kk * 16 + hl * 8);

  f32x16 oacc[2];
#pragma unroll
  for (int r = 0; r < 16; ++r) {
    oacc[0][r] = 0.f;
    oacc[1][r] = 0.f;
  }
  float l0 = 0.f, l1 = 0.f;

  auto stage = [&](int buf, int kt) {
#pragma unroll
    for (int i = 0; i < 2; ++i) {
      int c = i * 256 + t;
      int row = c >> 3;
      int ch = (c & 7) ^ (row & 7);
      gload16(Kp + (size_t)(b * Sc + kt * 64 + row) * 2048 + h * 64 + ch * 8,
              (const char*)Ksh[buf] + (i * 256 + wid * 64) * 16);
    }
#pragma unroll
    for (int i = 0; i < 2; ++i) {
      int c = i * 256 + t;
      int row = c >> 3;
      int ch = (c & 7) ^ (row & 7);
      gload16(Vt + (size_t)(h * 64 + row) * MSc + b * Sc + kt * 64 + ch * 8,
              (const char*)Vsh[buf] + (i * 256 + wid * 64) * 16);
    }
  };

  auto body = [&](int buf) {
    // ---- S^T[ks][q] = K Q^T
    f32x16 sacc[2];
#pragma unroll
    for (int mf = 0; mf < 2; ++mf)
#pragma unroll
      for (int r = 0; r < 16; ++r) sacc[mf][r] = 0.f;
#pragma unroll
    for (int kk = 0; kk < 4; ++kk)
#pragma unroll
      for (int mf = 0; mf < 2; ++mf) {
        int row = mf * 32 + ql;
        bf16x8 kf = *(const bf16x8*)((const char*)Ksh[buf] + row * 128 +
                                     ((kk * 32 + hl * 16) ^ ((row & 7) << 4)));
        sacc[mf] =
            __builtin_amdgcn_mfma_f32_32x32x16_bf16(kf, qf[kk], sacc[mf], 0, 0, 0);
      }

    // ---- p = exp2(s); accumulate l; pack to PV B-frags (layout verified r3)
    bf16x8 pb[4];
#pragma unroll
    for (int mf = 0; mf < 2; ++mf) {
      float p[16];
#pragma unroll
      for (int r = 0; r < 16; ++r) {
        p[r] = __builtin_exp2f(sacc[mf][r]);
        if (r & 1)
          l1 += p[r];
        else
          l0 += p[r];
      }
#pragma unroll
      for (int g = 0; g < 2; ++g) {
        uint32_t wa = cvtpk(p[8 * g + 0], p[8 * g + 1]);
        uint32_t wb = cvtpk(p[8 * g + 4], p[8 * g + 5]);
        uint32_t wc = cvtpk(p[8 * g + 2], p[8 * g + 3]);
        uint32_t wd = cvtpk(p[8 * g + 6], p[8 * g + 7]);
        plswap(wa, wb);
        plswap(wc, wd);
        u32x4 uw;
        uw.x = wa;  // j=0,1
        uw.y = wc;  // j=2,3
        uw.z = wb;  // j=4,5
        uw.w = wd;  // j=6,7
        pb[mf * 2 + g] = __builtin_bit_cast(bf16x8, uw);
      }
    }

    // ---- O^T += V^T P^T
#pragma unroll
    for (int kt2 = 0; kt2 < 4; ++kt2)
#pragma unroll
      for (int nh = 0; nh < 2; ++nh) {
        int row = nh * 32 + ql;
        bf16x8 vf = *(const bf16x8*)((const char*)Vsh[buf] + row * 128 +
                                     ((kt2 * 32 + hl * 16) ^ ((row & 7) << 4)));
        oacc[nh] =
            __builtin_amdgcn_mfma_f32_32x32x16_bf16(vf, pb[kt2], oacc[nh], 0, 0, 0);
      }
  };

  // 32 KV tiles; 4 bufs; 2 tiles per barrier period; stage issued first.
  stage(0, 0);
  stage(1, 1);
  __syncthreads();
  for (int q = 0; q < 8; ++q) {
    const int t0 = 4 * q;
    stage(2, t0 + 2);
    stage(3, t0 + 3);
    body(0);
    body(1);
    __syncthreads();
    if (t0 + 4 < 32) {
      stage(0, t0 + 4);
      stage(1, t0 + 5);
    }
    body(2);
    body(3);
    __syncthreads();
  }

  // ---- l: lane covers 32 ks-slots; lane^32 has the complement
  const float l_run = l0 + l1;
  const float l_tot = l_run + __shfl_xor(l_run, 32);
  const float inv_l = 1.f / l_tot;
#pragma unroll
  for (int nh = 0; nh < 2; ++nh)
#pragma unroll
    for (int g = 0; g < 4; ++g) {
      union {
        __bf16 hv[4];
        uint2 u;
      } w;
#pragma unroll
      for (int r = 0; r < 4; ++r)
        w.hv[r] = (__bf16)(oacc[nh][4 * g + r] * inv_l);
      int dh0 = nh * 32 + 8 * g + 4 * hl;
      *(uint2*)(ctx + (size_t)(b * Sc + q0w + ql) * Dc + h * 64 + dh0) = w.u;
    }
}

// =====================================================================
// LayerNorm over last dim (1024) of X0+X1+R (split-K partials + residual),
// one row per block (256 thr).
// MODE 0: write bf16 + f32 residual; MODE 1: f32 only.
// =====================================================================
template <int MODE>
__global__ __launch_bounds__(256) void ln_fused(const float* __restrict__ X0,
                                                const float* __restrict__ X1,
                                                const float* __restrict__ R,
                                                const float* __restrict__ gamma,
                                                const float* __restrict__ beta,
                                                __bf16* __restrict__ out_bf,
                                                float* __restrict__ out_f) {
  const int row = blockIdx.x;
  const int t = threadIdx.x;
  const f32x4 xv0 = *(const f32x4*)(X0 + (size_t)row * Dc + t * 4);
  const f32x4 xv1 = *(const f32x4*)(X1 + (size_t)row * Dc + t * 4);
  const f32x4 rv = *(const f32x4*)(R + (size_t)row * Dc + t * 4);
  float x[4];
  float s = 0.f, ss = 0.f;
#pragma unroll
  for (int i = 0; i < 4; ++i) {
    x[i] = xv0[i] + xv1[i] + rv[i];
    s += x[i];
    ss += x[i] * x[i];
  }
#pragma unroll
  for (int m = 1; m < 64; m <<= 1) {
    s += __shfl_xor(s, m);
    ss += __shfl_xor(ss, m);
  }
  __shared__ float sred[8];
  const int wid = t >> 6, lane = t & 63;
  if (lane == 0) {
    sred[wid * 2] = s;
    sred[wid * 2 + 1] = ss;
  }
  __syncthreads();
  s = sred[0] + sred[2] + sred[4] + sred[6];
  ss = sred[1] + sred[3] + sred[5] + sred[7];
  const float mu = s * (1.f / Dc);
  const float var = ss * (1.f / Dc) - mu * mu;
  const float rstd = rsqrtf(var + LN_EPS_C);
  const f32x4 gv = *(const f32x4*)(gamma + t * 4);
  const f32x4 bv = *(const f32x4*)(beta + t * 4);
#pragma unroll
  for (int i = 0; i < 4; ++i) {
    float y = (x[i] - mu) * rstd * gv[i] + bv[i];
    if (MODE == 0) {
      out_bf[(size_t)row * Dc + t * 4 + i] = (__bf16)y;
      out_f[(size_t)row * Dc + t * 4 + i] = y;
    } else {
      out_f[(size_t)row * Dc + t * 4 + i] = y;
    }
  }
}

// ---- transpose + cast all six weights: W[fi][fo] f32 -> Wt[fo][fi] bf16
__global__ __launch_bounds__(256) void wtrans(const float* __restrict__ w0,
                                              const float* __restrict__ w1,
                                              const float* __restrict__ w2,
                                              const float* __restrict__ w3,
                                              const float* __restrict__ w4,
                                              const float* __restrict__ w5,
                                              __bf16* __restrict__ out) {
  const float* ws[6] = {w0, w1, w2, w3, w4, w5};
  const float* w = ws[blockIdx.z];
  __bf16* o = out + (size_t)blockIdx.z * Dc * Dc;
  __shared__ float tile[32][33];
  const int tx = threadIdx.x, ty = threadIdx.y;  // 32 x 8
  const int c0 = blockIdx.x * 32, r0 = blockIdx.y * 32;
#pragma unroll
  for (int i = 0; i < 4; ++i)
    tile[ty + i * 8][tx] = w[(size_t)(r0 + ty + i * 8) * Dc + c0 + tx];
  __syncthreads();
#pragma unroll
  for (int i = 0; i < 4; ++i)
    o[(size_t)(c0 + ty + i * 8) * Dc + r0 + tx] = (__bf16)tile[tx][ty + i * 8];
}

// ---- f32 -> bf16 cast, 4 elements/thread
__global__ __launch_bounds__(256) void castq(const float* __restrict__ in,
                                             __bf16* __restrict__ out, int n4) {
  int i = blockIdx.x * blockDim.x + threadIdx.x;
  if (i < n4) {
    f32x4 v = *(const f32x4*)(in + (size_t)i * 4);
#pragma unroll
    for (int j = 0; j < 4; ++j) out[(size_t)i * 4 + j] = (__bf16)v[j];
  }
}

extern "C" void kernel_launch(void* const* d_in, const int* in_sizes, int n_in,
                              void* d_out, int out_size, void* d_ws,
                              size_t ws_size, hipStream_t stream) {
  const float* query = (const float*)d_in[0];
  const float* Wq = (const float*)d_in[1];
  const float* Wk = (const float*)d_in[2];
  const float* Wv = (const float*)d_in[3];
  const float* W1 = (const float*)d_in[4];
  const float* W2 = (const float*)d_in[5];
  const float* W3 = (const float*)d_in[6];
  const float* gamma = (const float*)d_in[7];
  const float* beta = (const float*)d_in[8];
  float* out = (float*)d_out;

  char* ws = (char*)d_ws;
  const size_t MB = 1u << 20;
  __bf16* Wt = (__bf16*)(ws);              // 6 x 2MB: [Wq;Wk;Wv;W1;W2;W3]^T
  __bf16* Xbf = (__bf16*)(ws + 12 * MB);   // 8MB
  __bf16* QKb = (__bf16*)(ws + 20 * MB);   // 16MB [4096x2048] = [Q*c | K]
  __bf16* Vt = (__bf16*)(ws + 36 * MB);    // 8MB  V^T [D, B*S]
  __bf16* Ctx = (__bf16*)(ws + 44 * MB);   // 8MB
  float* Ta = (float*)(ws + 52 * MB);      // 16MB  split-K partial 0
  __bf16* Rbf = (__bf16*)(ws + 68 * MB);   // 8MB
  float* Rf = (float*)(ws + 76 * MB);      // 16MB  f32 residual
  __bf16* H2 = (__bf16*)(ws + 92 * MB);    // 8MB
  float* Tb = (float*)(ws + 20 * MB);      // 16MB  partial 1, overlays QKb
                                           // (QKb dead after attn; Ta/Tb
                                           // consumed by LN before reuse)

  const int WD = Dc * Dc;

  wtrans<<<dim3(32, 32, 6), dim3(32, 8), 0, stream>>>(Wq, Wk, Wv, W1, W2, W3, Wt);
  castq<<<4096, 256, 0, stream>>>(query, Xbf, (MSc * Dc) / 4);
  // [Q*c | K] = X [Wq | Wk]  (fused, N=2048, 512 blocks, Q pre-scaled)
  gemm_bt<3, 128><<<32 * 16, 256, 0, stream>>>(Xbf, Wt, QKb, MSc, 2048, Dc);
  // V^T = Wv^T X^T : (A=Wv_t [D,D], Bt=X [B*S,D]) -> [D, B*S]
  gemm_bt<0, 64><<<8 * 64, 256, 0, stream>>>(Wt + 2 * WD, Xbf, Vt, Dc, MSc, Dc);
  attn_kernel<<<512, 256, 0, stream>>>(QKb, Vt, Ctx);
  // T1 = ctx W1 (f32, split-K=2 -> Ta+Tb, combined in LN)
  gemm_bt_sk2<64><<<2 * 32 * 16, 256, 0, stream>>>(Ctx, Wt + 3 * WD, Ta, Tb,
                                                   MSc, Dc, Dc);
  // residual = LN(Ta + Tb + query) -> Rbf (bf16) + Rf (f32)
  ln_fused<0><<<MSc, 256, 0, stream>>>(Ta, Tb, query, gamma, beta, Rbf, Rf);
  // H2 = relu(residual W2) (bf16)
  gemm_bt<2, 64><<<32 * 16, 256, 0, stream>>>(Rbf, Wt + 4 * WD, H2, MSc, Dc, Dc);
  // T3 = H2 W3 (f32, split-K=2)
  gemm_bt_sk2<64><<<2 * 32 * 16, 256, 0, stream>>>(H2, Wt + 5 * WD, Ta, Tb,
                                                   MSc, Dc, Dc);
  // out = LN(Ta + Tb + residual)
  ln_fused<1><<<MSc, 256, 0, stream>>>(Ta, Tb, Rf, gamma, beta, nullptr, out);
}

// Round 8
// 260.515 us; speedup vs baseline: 1.2919x; 1.1535x over previous
//
#include <hip/hip_runtime.h>
#include <stdint.h>

typedef __attribute__((ext_vector_type(8))) __bf16 bf16x8;
typedef __attribute__((ext_vector_type(4))) float f32x4;
typedef __attribute__((ext_vector_type(16))) float f32x16;
typedef __attribute__((ext_vector_type(4))) uint32_t u32x4;

#define DEVINL __device__ __forceinline__

constexpr int Bc = 2, Sc = 2048, Dc = 1024, Hc = 16;
constexpr int MSc = Bc * Sc;  // 4096 total rows
constexpr float LN_EPS_C = 1e-3f;
constexpr float QSCALE = 0.125f * 1.44269504f;  // 1/sqrt(64) * log2(e)

// ---- global -> LDS direct load, 16B per lane (wave-uniform LDS base).
DEVINL void gload16(const void* gsrc, const void* lds_dst) {
  auto g = (const __attribute__((address_space(1))) void*)(uintptr_t)gsrc;
  auto l = (__attribute__((address_space(3))) void*)(uint32_t)(uintptr_t)lds_dst;
  __builtin_amdgcn_global_load_lds(g, l, 16, 0, 0);
}

// packed f32 pair -> 2x bf16 in one u32
DEVINL uint32_t cvtpk(float lo, float hi) {
  uint32_t r;
  asm("v_cvt_pk_bf16_f32 %0, %1, %2" : "=v"(r) : "v"(lo), "v"(hi));
  return r;
}

// v_permlane32_swap: a[32:63] <-> b[0:31]  (non-volatile: pure on operands)
DEVINL void plswap(uint32_t& a, uint32_t& b) {
  asm("v_permlane32_swap_b32 %0, %1" : "+v"(a), "+v"(b));
}

// =====================================================================
// GEMM: C[M,N] = A[M,K] * Bt[N,K]^T   (A, Bt bf16 row-major, K-contiguous)
// 128xBN tile, BK=64, 256 thr = 4 waves 2x2, 16x16x32 bf16 MFMA.
// Double-buffered LDS, ONE barrier per K-step: stage(next) issued before
// compute(cur); the barrier drains the in-flight global_load_lds AND
// protects buffer reuse. LDS XOR-swizzle via pre-swizzled global source.
// EPI: 0 = bf16, 1 = f32, 2 = relu->bf16, 3 = bf16 with QSCALE on col<1024
// =====================================================================
template <int EPI, int BN>
__global__ __launch_bounds__(256) void gemm_bt(const __bf16* __restrict__ A,
                                               const __bf16* __restrict__ Bt,
                                               void* __restrict__ Cout,
                                               int M, int N, int K) {
  __shared__ __bf16 Ash[2][128 * 64];
  __shared__ __bf16 Bsh[2][BN * 64];
  constexpr int NF = BN / 32;
  const int t = threadIdx.x;
  const int lane = t & 63;
  const int wid = t >> 6;
  const int nbn = N / BN;
  const int bm = blockIdx.x / nbn, bn = blockIdx.x % nbn;
  const int m0 = bm * 128, n0 = bn * BN;
  const int wm = wid >> 1, wn = wid & 1;

  f32x4 acc[4][NF];
  f32x4 zero = {0.f, 0.f, 0.f, 0.f};
#pragma unroll
  for (int i = 0; i < 4; ++i)
#pragma unroll
    for (int j = 0; j < NF; ++j) acc[i][j] = zero;

  auto stage = [&](int buf, int k0) {
#pragma unroll
    for (int i = 0; i < 4; ++i) {
      int c = i * 256 + t;
      int row = c >> 3;
      int ch = (c & 7) ^ (row & 7);
      gload16(A + (size_t)(m0 + row) * K + k0 + ch * 8,
              (const char*)Ash[buf] + (i * 256 + wid * 64) * 16);
    }
#pragma unroll
    for (int i = 0; i < BN / 32; ++i) {
      int c = i * 256 + t;
      int row = c >> 3;
      int ch = (c & 7) ^ (row & 7);
      gload16(Bt + (size_t)(n0 + row) * K + k0 + ch * 8,
              (const char*)Bsh[buf] + (i * 256 + wid * 64) * 16);
    }
  };

  stage(0, 0);
  __syncthreads();
  for (int k0 = 0; k0 < K; k0 += 64) {
    const int buf = (k0 >> 6) & 1;
    if (k0 + 64 < K) stage(buf ^ 1, k0 + 64);
#pragma unroll
    for (int kk = 0; kk < 2; ++kk) {
      bf16x8 af[4], bfr[NF];
      const int colb = kk * 64 + (lane >> 4) * 16;
#pragma unroll
      for (int mf = 0; mf < 4; ++mf) {
        int row = wm * 64 + mf * 16 + (lane & 15);
        af[mf] = *(const bf16x8*)((const char*)Ash[buf] + row * 128 +
                                  (colb ^ ((row & 7) << 4)));
      }
#pragma unroll
      for (int nf = 0; nf < NF; ++nf) {
        int row = wn * (BN / 2) + nf * 16 + (lane & 15);
        bfr[nf] = *(const bf16x8*)((const char*)Bsh[buf] + row * 128 +
                                   (colb ^ ((row & 7) << 4)));
      }
#pragma unroll
      for (int mf = 0; mf < 4; ++mf)
#pragma unroll
        for (int nf = 0; nf < NF; ++nf)
          acc[mf][nf] = __builtin_amdgcn_mfma_f32_16x16x32_bf16(
              af[mf], bfr[nf], acc[mf][nf], 0, 0, 0);
    }
    __syncthreads();
  }
#pragma unroll
  for (int mf = 0; mf < 4; ++mf)
#pragma unroll
    for (int nf = 0; nf < NF; ++nf)
#pragma unroll
      for (int r = 0; r < 4; ++r) {
        int row = m0 + wm * 64 + mf * 16 + (lane >> 4) * 4 + r;
        int col = n0 + wn * (BN / 2) + nf * 16 + (lane & 15);
        float v = acc[mf][nf][r];
        if (EPI == 0)
          ((__bf16*)Cout)[(size_t)row * N + col] = (__bf16)v;
        else if (EPI == 1)
          ((float*)Cout)[(size_t)row * N + col] = v;
        else if (EPI == 2)
          ((__bf16*)Cout)[(size_t)row * N + col] = (__bf16)fmaxf(v, 0.f);
        else {
          if (col < 1024) v *= QSCALE;
          ((__bf16*)Cout)[(size_t)row * N + col] = (__bf16)v;
        }
      }
}

// =====================================================================
// Flash attention, swapped-QK 32x32, no-max softmax. 512 threads = 8 waves
// sharing the K/V LDS tiles (QBLK=256): 2 blocks/CU -> 4 waves/SIMD so
// barrier drains of one block hide under the other block's waves, and
// staging is 1 gload16/thread per K/V tile. XCD-clustered swizzle (r6:
// FETCH 102->12MB). Per-wave body identical to the r4-verified kernel.
// =====================================================================
__global__ __launch_bounds__(512, 4) void attn_kernel(const __bf16* __restrict__ QK,
                                                      const __bf16* __restrict__ Vt,
                                                      __bf16* __restrict__ ctx) {
  __shared__ __bf16 Ksh[2][64 * 64];
  __shared__ __bf16 Vsh[2][64 * 64];
  const int t = threadIdx.x, lane = t & 63, wid = t >> 6;  // wid 0..7
  // bijective swizzle: all 8 q-blocks of a (b,h) on one XCD
  const int flat = blockIdx.x;                        // 0..255
  const int bh = (flat & 7) * 4 + ((flat >> 3) & 3);  // 0..31
  const int qt = flat >> 5;                           // 0..7
  const int b = bh >> 4, h = bh & 15;
  const int q0w = qt * 256 + wid * 32;
  const int ql = lane & 31, hl = lane >> 5;

  const __bf16* Qp = QK;         // ld 2048, pre-scaled by QSCALE
  const __bf16* Kp = QK + 1024;  // ld 2048

  // Q as B-operand frags: col=q=lane&31, k=d = kk*16 + hl*8 + j
  bf16x8 qf[4];
#pragma unroll
  for (int kk = 0; kk < 4; ++kk)
    qf[kk] = *(const bf16x8*)(Qp + (size_t)(b * Sc + q0w + ql) * 2048 + h * 64 +
                              kk * 16 + hl * 8);

  f32x16 oacc[2];
#pragma unroll
  for (int r = 0; r < 16; ++r) {
    oacc[0][r] = 0.f;
    oacc[1][r] = 0.f;
  }
  float l0 = 0.f, l1 = 0.f, l2 = 0.f, l3 = 0.f;

  auto stage = [&](int buf, int kt) {
    // 512 threads x 16B = one 8KB tile per instruction
    const int row = t >> 3;
    const int ch = (t & 7) ^ (row & 7);
    gload16(Kp + (size_t)(b * Sc + kt * 64 + row) * 2048 + h * 64 + ch * 8,
            (const char*)Ksh[buf] + wid * 1024);
    gload16(Vt + (size_t)(h * 64 + row) * MSc + b * Sc + kt * 64 + ch * 8,
            (const char*)Vsh[buf] + wid * 1024);
  };

  auto body = [&](int buf) {
    // ---- S^T[ks][q] = K Q^T
    f32x16 sacc[2];
#pragma unroll
    for (int mf = 0; mf < 2; ++mf)
#pragma unroll
      for (int r = 0; r < 16; ++r) sacc[mf][r] = 0.f;
#pragma unroll
    for (int kk = 0; kk < 4; ++kk)
#pragma unroll
      for (int mf = 0; mf < 2; ++mf) {
        int row = mf * 32 + ql;
        bf16x8 kf = *(const bf16x8*)((const char*)Ksh[buf] + row * 128 +
                                     ((kk * 32 + hl * 16) ^ ((row & 7) << 4)));
        sacc[mf] =
            __builtin_amdgcn_mfma_f32_32x32x16_bf16(kf, qf[kk], sacc[mf], 0, 0, 0);
      }

    // ---- p = exp2(s); accumulate l (4 chains); pack to PV B-frags
    bf16x8 pb[4];
#pragma unroll
    for (int mf = 0; mf < 2; ++mf) {
      float p[16];
#pragma unroll
      for (int r = 0; r < 16; ++r) {
        p[r] = __builtin_exp2f(sacc[mf][r]);
        if ((r & 3) == 0)
          l0 += p[r];
        else if ((r & 3) == 1)
          l1 += p[r];
        else if ((r & 3) == 2)
          l2 += p[r];
        else
          l3 += p[r];
      }
#pragma unroll
      for (int g = 0; g < 2; ++g) {
        uint32_t wa = cvtpk(p[8 * g + 0], p[8 * g + 1]);
        uint32_t wb = cvtpk(p[8 * g + 4], p[8 * g + 5]);
        uint32_t wc = cvtpk(p[8 * g + 2], p[8 * g + 3]);
        uint32_t wd = cvtpk(p[8 * g + 6], p[8 * g + 7]);
        plswap(wa, wb);
        plswap(wc, wd);
        u32x4 uw;
        uw.x = wa;  // j=0,1
        uw.y = wc;  // j=2,3
        uw.z = wb;  // j=4,5
        uw.w = wd;  // j=6,7
        pb[mf * 2 + g] = __builtin_bit_cast(bf16x8, uw);
      }
    }

    // ---- O^T += V^T P^T
#pragma unroll
    for (int kt2 = 0; kt2 < 4; ++kt2)
#pragma unroll
      for (int nh = 0; nh < 2; ++nh) {
        int row = nh * 32 + ql;
        bf16x8 vf = *(const bf16x8*)((const char*)Vsh[buf] + row * 128 +
                                     ((kt2 * 32 + hl * 16) ^ ((row & 7) << 4)));
        oacc[nh] =
            __builtin_amdgcn_mfma_f32_32x32x16_bf16(vf, pb[kt2], oacc[nh], 0, 0, 0);
      }
  };

  stage(0, 0);
  __syncthreads();
  for (int kt = 0; kt < Sc / 64; ++kt) {
    const int buf = kt & 1;
    if (kt + 1 < Sc / 64) stage(buf ^ 1, kt + 1);
    body(buf);
    __syncthreads();
  }

  // ---- l: lane covers 32 ks-slots; lane^32 has the complement
  const float l_run = (l0 + l1) + (l2 + l3);
  const float l_tot = l_run + __shfl_xor(l_run, 32);
  const float inv_l = 1.f / l_tot;
#pragma unroll
  for (int nh = 0; nh < 2; ++nh)
#pragma unroll
    for (int g = 0; g < 4; ++g) {
      union {
        __bf16 hv[4];
        uint2 u;
      } w;
#pragma unroll
      for (int r = 0; r < 4; ++r)
        w.hv[r] = (__bf16)(oacc[nh][4 * g + r] * inv_l);
      int dh0 = nh * 32 + 8 * g + 4 * hl;
      *(uint2*)(ctx + (size_t)(b * Sc + q0w + ql) * Dc + h * 64 + dh0) = w.u;
    }
}

// =====================================================================
// LayerNorm over last dim (1024) of X+R, one row per block (256 thr).
// MODE 0: write bf16 + f32 residual; MODE 1: f32 only.
// =====================================================================
template <int MODE>
__global__ __launch_bounds__(256) void ln_fused(const float* __restrict__ X,
                                                const float* __restrict__ R,
                                                const float* __restrict__ gamma,
                                                const float* __restrict__ beta,
                                                __bf16* __restrict__ out_bf,
                                                float* __restrict__ out_f) {
  const int row = blockIdx.x;
  const int t = threadIdx.x;
  const f32x4 xv = *(const f32x4*)(X + (size_t)row * Dc + t * 4);
  const f32x4 rv = *(const f32x4*)(R + (size_t)row * Dc + t * 4);
  float x[4];
  float s = 0.f, ss = 0.f;
#pragma unroll
  for (int i = 0; i < 4; ++i) {
    x[i] = xv[i] + rv[i];
    s += x[i];
    ss += x[i] * x[i];
  }
#pragma unroll
  for (int m = 1; m < 64; m <<= 1) {
    s += __shfl_xor(s, m);
    ss += __shfl_xor(ss, m);
  }
  __shared__ float sred[8];
  const int wid = t >> 6, lane = t & 63;
  if (lane == 0) {
    sred[wid * 2] = s;
    sred[wid * 2 + 1] = ss;
  }
  __syncthreads();
  s = sred[0] + sred[2] + sred[4] + sred[6];
  ss = sred[1] + sred[3] + sred[5] + sred[7];
  const float mu = s * (1.f / Dc);
  const float var = ss * (1.f / Dc) - mu * mu;
  const float rstd = rsqrtf(var + LN_EPS_C);
  const f32x4 gv = *(const f32x4*)(gamma + t * 4);
  const f32x4 bv = *(const f32x4*)(beta + t * 4);
#pragma unroll
  for (int i = 0; i < 4; ++i) {
    float y = (x[i] - mu) * rstd * gv[i] + bv[i];
    if (MODE == 0) {
      out_bf[(size_t)row * Dc + t * 4 + i] = (__bf16)y;
      out_f[(size_t)row * Dc + t * 4 + i] = y;
    } else {
      out_f[(size_t)row * Dc + t * 4 + i] = y;
    }
  }
}

// ---- transpose + cast all six weights: W[fi][fo] f32 -> Wt[fo][fi] bf16
__global__ __launch_bounds__(256) void wtrans(const float* __restrict__ w0,
                                              const float* __restrict__ w1,
                                              const float* __restrict__ w2,
                                              const float* __restrict__ w3,
                                              const float* __restrict__ w4,
                                              const float* __restrict__ w5,
                                              __bf16* __restrict__ out) {
  const float* ws[6] = {w0, w1, w2, w3, w4, w5};
  const float* w = ws[blockIdx.z];
  __bf16* o = out + (size_t)blockIdx.z * Dc * Dc;
  __shared__ float tile[32][33];
  const int tx = threadIdx.x, ty = threadIdx.y;  // 32 x 8
  const int c0 = blockIdx.x * 32, r0 = blockIdx.y * 32;
#pragma unroll
  for (int i = 0; i < 4; ++i)
    tile[ty + i * 8][tx] = w[(size_t)(r0 + ty + i * 8) * Dc + c0 + tx];
  __syncthreads();
#pragma unroll
  for (int i = 0; i < 4; ++i)
    o[(size_t)(c0 + ty + i * 8) * Dc + r0 + tx] = (__bf16)tile[tx][ty + i * 8];
}

// ---- f32 -> bf16 cast, 4 elements/thread
__global__ __launch_bounds__(256) void castq(const float* __restrict__ in,
                                             __bf16* __restrict__ out, int n4) {
  int i = blockIdx.x * blockDim.x + threadIdx.x;
  if (i < n4) {
    f32x4 v = *(const f32x4*)(in + (size_t)i * 4);
#pragma unroll
    for (int j = 0; j < 4; ++j) out[(size_t)i * 4 + j] = (__bf16)v[j];
  }
}

extern "C" void kernel_launch(void* const* d_in, const int* in_sizes, int n_in,
                              void* d_out, int out_size, void* d_ws,
                              size_t ws_size, hipStream_t stream) {
  const float* query = (const float*)d_in[0];
  const float* Wq = (const float*)d_in[1];
  const float* Wk = (const float*)d_in[2];
  const float* Wv = (const float*)d_in[3];
  const float* W1 = (const float*)d_in[4];
  const float* W2 = (const float*)d_in[5];
  const float* W3 = (const float*)d_in[6];
  const float* gamma = (const float*)d_in[7];
  const float* beta = (const float*)d_in[8];
  float* out = (float*)d_out;

  char* ws = (char*)d_ws;
  const size_t MB = 1u << 20;
  __bf16* Wt = (__bf16*)(ws);              // 6 x 2MB: [Wq;Wk;Wv;W1;W2;W3]^T
  __bf16* Xbf = (__bf16*)(ws + 12 * MB);   // 8MB
  __bf16* QKb = (__bf16*)(ws + 20 * MB);   // 16MB [4096x2048] = [Q*c | K]
  __bf16* Vt = (__bf16*)(ws + 36 * MB);    // 8MB  V^T [D, B*S]
  __bf16* Ctx = (__bf16*)(ws + 44 * MB);   // 8MB
  float* T1 = (float*)(ws + 52 * MB);      // 16MB (reused for T3)
  __bf16* Rbf = (__bf16*)(ws + 68 * MB);   // 8MB
  float* Rf = (float*)(ws + 76 * MB);      // 16MB  f32 residual
  __bf16* H2 = (__bf16*)(ws + 92 * MB);    // 8MB

  const int WD = Dc * Dc;

  wtrans<<<dim3(32, 32, 6), dim3(32, 8), 0, stream>>>(Wq, Wk, Wv, W1, W2, W3, Wt);
  castq<<<4096, 256, 0, stream>>>(query, Xbf, (MSc * Dc) / 4);
  // [Q*c | K] = X [Wq | Wk]  (fused, N=2048, 1024 blocks, Q pre-scaled)
  gemm_bt<3, 64><<<32 * 32, 256, 0, stream>>>(Xbf, Wt, QKb, MSc, 2048, Dc);
  // V^T = Wv^T X^T : (A=Wv_t [D,D], Bt=X [B*S,D]) -> [D, B*S]
  gemm_bt<0, 64><<<8 * 64, 256, 0, stream>>>(Wt + 2 * WD, Xbf, Vt, Dc, MSc, Dc);
  attn_kernel<<<256, 512, 0, stream>>>(QKb, Vt, Ctx);
  // T1 = ctx W1 (f32)
  gemm_bt<1, 64><<<32 * 16, 256, 0, stream>>>(Ctx, Wt + 3 * WD, T1, MSc, Dc, Dc);
  // residual = LN(T1 + query) -> Rbf (bf16) + Rf (f32)
  ln_fused<0><<<MSc, 256, 0, stream>>>(T1, query, gamma, beta, Rbf, Rf);
  // H2 = relu(residual W2) (bf16)
  gemm_bt<2, 64><<<32 * 16, 256, 0, stream>>>(Rbf, Wt + 4 * WD, H2, MSc, Dc, Dc);
  // T3 = H2 W3 (f32)
  gemm_bt<1, 64><<<32 * 16, 256, 0, stream>>>(H2, Wt + 5 * WD, T1, MSc, Dc, Dc);
  // out = LN(T3 + residual)
  ln_fused<1><<<MSc, 256, 0, stream>>>(T1, Rf, gamma, beta, nullptr, out);
}